// Round 6
// baseline (148.968 us; speedup 1.0000x reference)
//
#include <hip/hip_runtime.h>
#include <math.h>

#define PROJ 8192
#define NB   16
#define NC   512
#define HW   196    // 14*14
#define NKC  7      // K chunks of 32 (196 zero-padded to 224)
#define LST  40     // LDS row stride in bf16 elems (80 B = 5*16: b128-aligned, 2-way banks = free)

typedef __attribute__((ext_vector_type(8))) short bf16x8;   // MFMA A/B frag
typedef __attribute__((ext_vector_type(4))) short short4v;
typedef __attribute__((ext_vector_type(4))) float f32x4;    // MFMA C/D frag

__device__ __forceinline__ unsigned bf16_rne(float f) {
    unsigned u = __builtin_bit_cast(unsigned, f);
    return (u + 0x7fffu + ((u >> 16) & 1u)) >> 16;
}

// ===========================================================================
// Single fused kernel. grid = 256 blocks (1/CU guaranteed) x 1024 threads.
//  P1: split-bf16 MFMA 128x128 Gram tile (signs folded into staging) ->
//      sign-free scatter into private 32KB LDS sketch -> dense dump to ws.
//  Grid barrier A (poison-safe flag protocol; release-store / acquire-load).
//  P2: sum 16 partials/bin (rotated to dodge channel hotspot) + signed sqrt
//      (kept in registers) + per-block ssq partial.
//  Grid barrier B.
//  P3: y = o / max(||y_b||, 1e-12)   (single write of d_out).
// ===========================================================================
__global__ __launch_bounds__(1024)
void cbp_all(const float* __restrict__ x,
             const float* __restrict__ s1,
             const float* __restrict__ s2,
             const int*   __restrict__ h1,
             const int*   __restrict__ h2,
             float* __restrict__ y,
             float* __restrict__ ws,
             int*   __restrict__ f1,
             int*   __restrict__ f2,
             float* __restrict__ ssqp) {
    __shared__ float sk[PROJ];         // 32 KB private sketch (reused as red buf)
    __shared__ short Ah[128 * LST];    // 10 KB each: hi/lo bf16 stages
    __shared__ short Al[128 * LST];
    __shared__ short Bh[128 * LST];
    __shared__ short Bl[128 * LST];
    __shared__ int   lh1[128], lh2[128];
    __shared__ float lsA[128], lsB[128];

    const int tid = threadIdx.x;
    const int blk = blockIdx.x;
    const int b   = blk >> 4;
    const int I   = (blk >> 2) & 3;
    const int J   = blk & 3;
    const int c1base = I * 128;
    const int c2base = J * 128;

    const int lane = tid & 63;
    const int wave = tid >> 6;         // 0..15
    const int quad = lane >> 4;
    const int l15  = lane & 15;
    const int wr   = (wave >> 2) * 32; // wave's 32x32 quadrant
    const int wc   = (wave & 3) * 32;

    for (int i = tid; i < PROJ; i += 1024) sk[i] = 0.f;
    if (tid < 128) {
        lh1[tid] = h1[c1base + tid];  lsA[tid] = s1[c1base + tid];
        lh2[tid] = h2[c2base + tid];  lsB[tid] = s2[c2base + tid];
    }

    const float* xa = x + ((size_t)b * NC + c1base) * HW;
    const float* xb = x + ((size_t)b * NC + c2base) * HW;

    f32x4 acc[2][2];
#pragma unroll
    for (int i = 0; i < 2; ++i)
#pragma unroll
        for (int j = 0; j < 2; ++j) acc[i][j] = (f32x4){0.f, 0.f, 0.f, 0.f};

    const int sr = tid >> 3;           // staging row 0..127
    const int sq = tid & 7;            // staging float4 slot 0..7

    // ---------------- Phase 1: Gram + sketch ----------------
    for (int kc = 0; kc < NKC; ++kc) {
        const int k0 = kc * 32;
        __syncthreads();               // also covers lh/ls stores on kc==0
        {
            const int kk = k0 + 4 * sq;
            float4 va = {0.f,0.f,0.f,0.f}, vb = {0.f,0.f,0.f,0.f};
            if (kk + 3 < HW) {         // zero-pad K 196->224
                va = *(const float4*)&xa[sr * HW + kk];
                vb = *(const float4*)&xb[sr * HW + kk];
            }
            const float sA = lsA[sr], sB = lsB[sr];   // fold signs (exact)
            const float fa[4] = {va.x * sA, va.y * sA, va.z * sA, va.w * sA};
            const float fb[4] = {vb.x * sB, vb.y * sB, vb.z * sB, vb.w * sB};
            short4v ah, al, bh, bl;
#pragma unroll
            for (int c = 0; c < 4; ++c) {
                const unsigned ha_ = bf16_rne(fa[c]);
                ah[c] = (short)ha_;
                al[c] = (short)bf16_rne(fa[c] - __builtin_bit_cast(float, ha_ << 16));
                const unsigned hb_ = bf16_rne(fb[c]);
                bh[c] = (short)hb_;
                bl[c] = (short)bf16_rne(fb[c] - __builtin_bit_cast(float, hb_ << 16));
            }
            *(short4v*)&Ah[sr * LST + 4 * sq] = ah;
            *(short4v*)&Al[sr * LST + 4 * sq] = al;
            *(short4v*)&Bh[sr * LST + 4 * sq] = bh;
            *(short4v*)&Bl[sr * LST + 4 * sq] = bl;
        }
        __syncthreads();

        bf16x8 ahf[2], alf[2], bhf[2], blf[2];
#pragma unroll
        for (int i = 0; i < 2; ++i) {
            const int ra = wr + i * 16 + l15;
            const int rb = wc + i * 16 + l15;
            ahf[i] = *(const bf16x8*)&Ah[ra * LST + quad * 8];
            alf[i] = *(const bf16x8*)&Al[ra * LST + quad * 8];
            bhf[i] = *(const bf16x8*)&Bh[rb * LST + quad * 8];
            blf[i] = *(const bf16x8*)&Bl[rb * LST + quad * 8];
        }
#pragma unroll
        for (int i = 0; i < 2; ++i)
#pragma unroll
            for (int j = 0; j < 2; ++j) {
                acc[i][j] = __builtin_amdgcn_mfma_f32_16x16x32_bf16(ahf[i], bhf[j], acc[i][j], 0, 0, 0);
                acc[i][j] = __builtin_amdgcn_mfma_f32_16x16x32_bf16(ahf[i], blf[j], acc[i][j], 0, 0, 0);
                acc[i][j] = __builtin_amdgcn_mfma_f32_16x16x32_bf16(alf[i], bhf[j], acc[i][j], 0, 0, 0);
            }
    }
    __syncthreads();

    // Scatter (signs already folded): C/D layout col=lane&15, row=quad*4+reg.
#pragma unroll
    for (int i = 0; i < 2; ++i) {
        const int lr0 = wr + i * 16 + quad * 4;
#pragma unroll
        for (int j = 0; j < 2; ++j) {
            const int h2v = lh2[wc + j * 16 + l15];
#pragma unroll
            for (int rg = 0; rg < 4; ++rg) {
                const int bin = (lh1[lr0 + rg] + h2v) & (PROJ - 1);
                atomicAdd(&sk[bin], acc[i][j][rg]);   // ds_add_f32
            }
        }
    }
    __syncthreads();

    {   // dense coalesced dump of the partial sketch
        float4* dst = (float4*)(ws + (size_t)blk * PROJ);
        const float4* src = (const float4*)sk;
        for (int i = tid; i < PROJ / 4; i += 1024) dst[i] = src[i];
    }

    // ---------------- Grid barrier A ----------------
    __syncthreads();                                   // all waves' work done
    if (tid == 0) {
        // release-store publishes this block's ws dump (device scope)
        __hip_atomic_store(&f1[blk], 1, __ATOMIC_RELEASE, __HIP_MEMORY_SCOPE_AGENT);
    }
    if (tid < 256) {
        int spins = 0;
        while (__hip_atomic_load(&f1[tid], __ATOMIC_ACQUIRE, __HIP_MEMORY_SCOPE_AGENT) != 1)
            if (++spins > (1 << 26)) break;            // failsafe: no infinite hang
    }
    __syncthreads();

    // ---------------- Phase 2: reduce + signed sqrt + ssq partial -----------
    float o = 0.f;
    if (tid < 512) {
        const int bin = (blk & 15) * 512 + tid;
        float s = 0.f;
#pragma unroll
        for (int p = 0; p < 16; ++p) {
            const int p2 = (p + blk) & 15;             // rotate: no channel hotspot
            s += ws[((size_t)(b * 16 + p2)) * PROJ + bin];
        }
        const float m = sqrtf(fabsf(s) + 1e-8f);
        o = (s > 0.f) ? m : (s < 0.f ? -m : 0.f);      // sign(0)=0
    }
    float* red = sk;                                   // reuse sketch LDS
    red[tid] = o * o;
    __syncthreads();
#pragma unroll
    for (int st = 512; st >= 1; st >>= 1) {
        if (tid < st) red[tid] += red[tid + st];
        __syncthreads();
    }
    if (tid == 0) ssqp[blk] = red[0];

    // ---------------- Grid barrier B ----------------
    __syncthreads();
    if (tid == 0) {
        __hip_atomic_store(&f2[blk], 1, __ATOMIC_RELEASE, __HIP_MEMORY_SCOPE_AGENT);
    }
    if (tid < 256) {
        int spins = 0;
        while (__hip_atomic_load(&f2[tid], __ATOMIC_ACQUIRE, __HIP_MEMORY_SCOPE_AGENT) != 1)
            if (++spins > (1 << 26)) break;
    }
    __syncthreads();

    // ---------------- Phase 3: L2 normalize, single y write ----------------
    if (tid < 16) red[tid] = ssqp[b * 16 + tid];
    __syncthreads();
    if (tid == 0) {
        float ssq = 0.f;
#pragma unroll
        for (int t = 0; t < 16; ++t) ssq += red[t];
        red[0] = 1.0f / fmaxf(sqrtf(ssq), 1e-12f);
    }
    __syncthreads();
    const float inv = red[0];
    if (tid < 512)
        y[(size_t)b * PROJ + (blk & 15) * 512 + tid] = o * inv;
}

// ---------------------------------------------------------------------------
extern "C" void kernel_launch(void* const* d_in, const int* in_sizes, int n_in,
                              void* d_out, int out_size, void* d_ws, size_t ws_size,
                              hipStream_t stream) {
    const float* x  = (const float*)d_in[0];
    const float* s1 = (const float*)d_in[1];
    const float* s2 = (const float*)d_in[2];
    const int*   h1 = (const int*)d_in[3];
    const int*   h2 = (const int*)d_in[4];
    float* y  = (float*)d_out;                       // [16, 8192]
    float* ws = (float*)d_ws;                        // 256 sketches = 8 MB
    int*   f1 = (int*)(ws + (size_t)256 * PROJ);     // +256 ints (poisoned 0xAA != 1)
    int*   f2 = f1 + 256;                            // +256 ints
    float* ssqp = (float*)(f2 + 256);                // +256 floats

    hipLaunchKernelGGL(cbp_all, dim3(256), dim3(1024), 0, stream,
                       x, s1, s2, h1, h2, y, ws, f1, f2, ssqp);
}

// Round 7
// 104.206 us; speedup vs baseline: 1.4296x; 1.4296x over previous
//
#include <hip/hip_runtime.h>
#include <math.h>

#define PROJ 8192
#define NB   16
#define NC   512
#define HW   196    // 14*14
#define NKC  7      // K chunks of 32 (196 zero-padded to 224)
#define LST  40     // LDS row stride in bf16 elems (80 B: b128-aligned, 2-way banks = free)

typedef __attribute__((ext_vector_type(8))) short bf16x8;   // MFMA A/B frag
typedef __attribute__((ext_vector_type(4))) short short4v;
typedef __attribute__((ext_vector_type(4))) float f32x4;    // MFMA C/D frag

__device__ __forceinline__ unsigned bf16_rne(float f) {
    unsigned u = __builtin_bit_cast(unsigned, f);
    return (u + 0x7fffu + ((u >> 16) & 1u)) >> 16;
}

// ---------------------------------------------------------------------------
// Kernel 1: split-bf16 MFMA Gram (128x128 tile) + scatter into private LDS
// sketch -> dense dump.  grid = 256 blocks x 512 threads (8 waves = 2/SIMD).
// Physical block -> (batch,tile) swizzled so blk%8 (XCD) pins a batch pair:
//   b = 2*(blk&7) + (blk>>7),  tile = (blk>>3)&15
// K-loop software-pipelined: chunk k+1 global loads issue before chunk k MFMA.
// Signs folded into staged bf16 (exact: sign-bit flip).
// ---------------------------------------------------------------------------
__global__ __launch_bounds__(512, 2)
void cbp_gram_mfma(const float* __restrict__ x,
                   const float* __restrict__ s1,
                   const float* __restrict__ s2,
                   const int*   __restrict__ h1,
                   const int*   __restrict__ h2,
                   float* __restrict__ ws) {
    __shared__ float sk[PROJ];         // 32 KB private sketch
    __shared__ short Ah[128 * LST];    // 10 KB each
    __shared__ short Al[128 * LST];
    __shared__ short Bh[128 * LST];
    __shared__ short Bl[128 * LST];
    __shared__ int   lh1[128], lh2[128];
    __shared__ float lsA[128], lsB[128];

    const int tid = threadIdx.x;
    const int blk = blockIdx.x;
    const int b    = 2 * (blk & 7) + (blk >> 7);   // XCD-pinned batch
    const int tile = (blk >> 3) & 15;
    const int I = tile >> 2, J = tile & 3;
    const int c1base = I * 128;
    const int c2base = J * 128;

    const int lane = tid & 63;
    const int wave = tid >> 6;         // 0..7
    const int quad = lane >> 4;
    const int l15  = lane & 15;
    const int wr   = (wave >> 1) * 32; // wave's 32x64 sub-tile
    const int wc   = (wave & 1) * 64;

    for (int i = tid; i < PROJ; i += 512) sk[i] = 0.f;
    if (tid < 128) {
        lh1[tid] = h1[c1base + tid];  lsA[tid] = s1[c1base + tid];
        lh2[tid] = h2[c2base + tid];  lsB[tid] = s2[c2base + tid];
    }

    const float* xa = x + ((size_t)b * NC + c1base) * HW;
    const float* xb = x + ((size_t)b * NC + c2base) * HW;

    f32x4 acc[2][4];
#pragma unroll
    for (int i = 0; i < 2; ++i)
#pragma unroll
        for (int j = 0; j < 4; ++j) acc[i][j] = (f32x4){0.f, 0.f, 0.f, 0.f};

    // Staging assignment: thread handles rows sr0 and sr0+64, float4 slot sq.
    const int sr0 = tid >> 3;          // 0..63
    const int sq  = tid & 7;           // 0..7

    float4 pa[2], pb[2];
    {   // prologue: load chunk 0
        const int kk = 4 * sq;
        const bool ok = (kk + 3 < HW);
#pragma unroll
        for (int h = 0; h < 2; ++h) {
            const int r = sr0 + 64 * h;
            pa[h] = ok ? *(const float4*)&xa[r * HW + kk] : (float4){0.f,0.f,0.f,0.f};
            pb[h] = ok ? *(const float4*)&xb[r * HW + kk] : (float4){0.f,0.f,0.f,0.f};
        }
    }

    for (int kc = 0; kc < NKC; ++kc) {
        __syncthreads();               // LDS free; also covers lh/ls on kc==0
        // Convert + store current chunk (signs folded; exact for +-1).
#pragma unroll
        for (int h = 0; h < 2; ++h) {
            const int r = sr0 + 64 * h;
            const float sA = lsA[r], sB = lsB[r];
            const float fa[4] = {pa[h].x*sA, pa[h].y*sA, pa[h].z*sA, pa[h].w*sA};
            const float fb[4] = {pb[h].x*sB, pb[h].y*sB, pb[h].z*sB, pb[h].w*sB};
            short4v ah, al, bh, bl;
#pragma unroll
            for (int c = 0; c < 4; ++c) {
                const unsigned ha_ = bf16_rne(fa[c]);
                ah[c] = (short)ha_;
                al[c] = (short)bf16_rne(fa[c] - __builtin_bit_cast(float, ha_ << 16));
                const unsigned hb_ = bf16_rne(fb[c]);
                bh[c] = (short)hb_;
                bl[c] = (short)bf16_rne(fb[c] - __builtin_bit_cast(float, hb_ << 16));
            }
            *(short4v*)&Ah[r * LST + 4 * sq] = ah;
            *(short4v*)&Al[r * LST + 4 * sq] = al;
            *(short4v*)&Bh[r * LST + 4 * sq] = bh;
            *(short4v*)&Bl[r * LST + 4 * sq] = bl;
        }
        // Prefetch next chunk while this chunk computes.
        if (kc + 1 < NKC) {
            const int kk = (kc + 1) * 32 + 4 * sq;
            const bool ok = (kk + 3 < HW);
#pragma unroll
            for (int h = 0; h < 2; ++h) {
                const int r = sr0 + 64 * h;
                pa[h] = ok ? *(const float4*)&xa[r * HW + kk] : (float4){0.f,0.f,0.f,0.f};
                pb[h] = ok ? *(const float4*)&xb[r * HW + kk] : (float4){0.f,0.f,0.f,0.f};
            }
        }
        __syncthreads();

        bf16x8 ahf[2], alf[2], bhf[4], blf[4];
#pragma unroll
        for (int i = 0; i < 2; ++i) {
            const int ra = wr + i * 16 + l15;
            ahf[i] = *(const bf16x8*)&Ah[ra * LST + quad * 8];
            alf[i] = *(const bf16x8*)&Al[ra * LST + quad * 8];
        }
#pragma unroll
        for (int j = 0; j < 4; ++j) {
            const int rb = wc + j * 16 + l15;
            bhf[j] = *(const bf16x8*)&Bh[rb * LST + quad * 8];
            blf[j] = *(const bf16x8*)&Bl[rb * LST + quad * 8];
        }
#pragma unroll
        for (int i = 0; i < 2; ++i)
#pragma unroll
            for (int j = 0; j < 4; ++j) {
                acc[i][j] = __builtin_amdgcn_mfma_f32_16x16x32_bf16(ahf[i], bhf[j], acc[i][j], 0, 0, 0);
                acc[i][j] = __builtin_amdgcn_mfma_f32_16x16x32_bf16(ahf[i], blf[j], acc[i][j], 0, 0, 0);
                acc[i][j] = __builtin_amdgcn_mfma_f32_16x16x32_bf16(alf[i], bhf[j], acc[i][j], 0, 0, 0);
            }
    }
    __syncthreads();

    // Scatter (signs pre-folded): C/D layout col=lane&15, row=quad*4+reg.
#pragma unroll
    for (int i = 0; i < 2; ++i) {
        const int lr0 = wr + i * 16 + quad * 4;
#pragma unroll
        for (int j = 0; j < 4; ++j) {
            const int h2v = lh2[wc + j * 16 + l15];
#pragma unroll
            for (int rg = 0; rg < 4; ++rg) {
                const int bin = (lh1[lr0 + rg] + h2v) & (PROJ - 1);
                atomicAdd(&sk[bin], acc[i][j][rg]);   // ds_add_f32
            }
        }
    }
    __syncthreads();

    float4* dst = (float4*)(ws + (size_t)blk * PROJ);
    const float4* src = (const float4*)sk;
    for (int i = tid; i < PROJ / 4; i += 512) dst[i] = src[i];
}

// ---------------------------------------------------------------------------
// Kernel 2: sum 16 partials/bin (swizzled layout) + signed sqrt + ssq partial.
// grid = 512 blocks x 256 threads.
// ---------------------------------------------------------------------------
__global__ __launch_bounds__(256)
void cbp_reduce(const float* __restrict__ ws, float* __restrict__ y,
                float* __restrict__ ssqp) {
    const int blk = blockIdx.x;
    const int b   = blk >> 5;
    const int seg = blk & 31;
    const int tid = threadIdx.x;
    const int bin = seg * 256 + tid;

    // physical partial block for (b, t): ((b&1)<<7) | (t<<3) | (b>>1)
    const int pbase = ((b & 1) << 7) | (b >> 1);
    float s = 0.f;
#pragma unroll
    for (int t = 0; t < 16; ++t)
        s += ws[(size_t)(pbase | (t << 3)) * PROJ + bin];

    const float m = sqrtf(fabsf(s) + 1e-8f);
    const float o = (s > 0.f) ? m : (s < 0.f ? -m : 0.f);   // sign(0)=0
    y[b * PROJ + bin] = o;

    __shared__ float red[256];
    red[tid] = o * o;
    __syncthreads();
#pragma unroll
    for (int st = 128; st >= 1; st >>= 1) {
        if (tid < st) red[tid] += red[tid + st];
        __syncthreads();
    }
    if (tid == 0) ssqp[blk] = red[0];
}

// ---------------------------------------------------------------------------
// Kernel 3: scale each batch row by 1/max(||y_b||, 1e-12). grid = 32.
// ---------------------------------------------------------------------------
__global__ __launch_bounds__(256)
void cbp_normalize(float* __restrict__ y, const float* __restrict__ ssqp) {
    const int b   = blockIdx.x >> 1;
    const int off = (blockIdx.x & 1) * 4096;
    const int tid = threadIdx.x;
    float ssq = 0.f;
#pragma unroll
    for (int i = 0; i < 32; ++i) ssq += ssqp[b * 32 + i];
    const float inv = 1.0f / fmaxf(sqrtf(ssq), 1e-12f);

    float4* row = (float4*)&y[(size_t)b * PROJ + off];
#pragma unroll
    for (int j = 0; j < 4; ++j) {
        float4 v = row[j * 256 + tid];
        v.x *= inv; v.y *= inv; v.z *= inv; v.w *= inv;
        row[j * 256 + tid] = v;
    }
}

// ---------------------------------------------------------------------------
extern "C" void kernel_launch(void* const* d_in, const int* in_sizes, int n_in,
                              void* d_out, int out_size, void* d_ws, size_t ws_size,
                              hipStream_t stream) {
    const float* x  = (const float*)d_in[0];
    const float* s1 = (const float*)d_in[1];
    const float* s2 = (const float*)d_in[2];
    const int*   h1 = (const int*)d_in[3];
    const int*   h2 = (const int*)d_in[4];
    float* y    = (float*)d_out;                   // [16, 8192]
    float* ws   = (float*)d_ws;                    // 256 partial sketches (8 MB)
    float* ssqp = ws + (size_t)256 * PROJ;         // + 512 floats

    hipLaunchKernelGGL(cbp_gram_mfma, dim3(256), dim3(512), 0, stream,
                       x, s1, s2, h1, h2, ws);
    hipLaunchKernelGGL(cbp_reduce, dim3(512), dim3(256), 0, stream, ws, y, ssqp);
    hipLaunchKernelGGL(cbp_normalize, dim3(32), dim3(256), 0, stream, y, ssqp);
}